// Round 19
// baseline (133.494 us; speedup 1.0000x reference)
//
#include <hip/hip_runtime.h>
#include <hip/hip_bf16.h>
#include <cmath>

#define D_MODEL 1024
#define N_HEADS 16
#define D_HEAD  64
#define BATCH   2
#define SEQ     2048
#define M_TOT   (BATCH*SEQ)   // 4096
#define NELT    ((size_t)M_TOT * D_MODEL)   // 4M elements

typedef __attribute__((ext_vector_type(8))) short short8;   // 8 bf16 (4 VGPRs)
typedef __attribute__((ext_vector_type(4))) float f32x4;

// Q pre-scale: 1/sqrt(64) * log2(e)  (softmax computed base-2)
#define QSCALE (0.125f * 1.44269504088896f)

static __device__ __forceinline__ ushort f2bf(float f) {
    __hip_bfloat16 h = __float2bfloat16(f);   // RNE
    return *reinterpret_cast<ushort*>(&h);
}

// Raw v_exp_f32 (2^x) — no libm denormal-fixup wrapper (round-13 win).
static __device__ __forceinline__ float exp2_raw(float x) {
    return __builtin_amdgcn_exp2f(x);
}

static __device__ __forceinline__ void gload_lds16(const void* g, void* l) {
    __builtin_amdgcn_global_load_lds((const __attribute__((address_space(1))) unsigned*)g,
                                     (__attribute__((address_space(3))) unsigned*)l,
                                     16, 0, 0);
}

// ---------------------------------------------------------------------------
// prep: z<4 -> transpose+convert weight z to Wt [N][K] bf16;
//       z==4 -> convert a slab of x to bf16.
// ---------------------------------------------------------------------------
__global__ __launch_bounds__(256)
void prep_kernel(const float* __restrict__ x,
                 const float* __restrict__ W0, const float* __restrict__ W1,
                 const float* __restrict__ W2, const float* __restrict__ W3,
                 ushort* __restrict__ xb, ushort* __restrict__ Wt0)
{
    __shared__ float Ts[64][65];
    const int z = blockIdx.z;
    const int t = threadIdx.x;

    if (z == 4) {
        const int slab = blockIdx.y * 16 + blockIdx.x;
#pragma unroll
        for (int u = 0; u < 16; ++u) {
            const int i = slab * 4096 + u * 256 + t;
            const float4 v = ((const float4*)x)[i];
            ushort4 uo;
            uo.x = f2bf(v.x); uo.y = f2bf(v.y); uo.z = f2bf(v.z); uo.w = f2bf(v.w);
            ((ushort4*)xb)[i] = uo;
        }
        return;
    }

    const float* W = (z == 0) ? W0 : (z == 1) ? W1 : (z == 2) ? W2 : W3;
    ushort* Wt = Wt0 + (size_t)z * D_MODEL * D_MODEL;

    const int n0 = blockIdx.x * 64;
    const int k0 = blockIdx.y * 64;
    const int rr = t >> 4;
    const int c4 = (t & 15) * 4;

#pragma unroll
    for (int i = 0; i < 4; ++i) {
        const int r = rr + i * 16;
        const float4 v = *(const float4*)&W[(size_t)(k0 + r) * D_MODEL + n0 + c4];
        Ts[r][c4 + 0] = v.x; Ts[r][c4 + 1] = v.y;
        Ts[r][c4 + 2] = v.z; Ts[r][c4 + 3] = v.w;
    }
    __syncthreads();
#pragma unroll
    for (int i = 0; i < 4; ++i) {
        const int nn = rr + i * 16;
        ushort4 u;
        u.x = f2bf(Ts[c4 + 0][nn]); u.y = f2bf(Ts[c4 + 1][nn]);
        u.z = f2bf(Ts[c4 + 2][nn]); u.w = f2bf(Ts[c4 + 3][nn]);
        *(ushort4*)&Wt[(size_t)(n0 + nn) * D_MODEL + k0 + c4] = u;
    }
}

// ---------------------------------------------------------------------------
// Merged QKV GEMM: bf16 MFMA, 128x128 tile, BK=64, 4 waves. (unchanged)
// ---------------------------------------------------------------------------
__global__ __launch_bounds__(256)
void gemm_qkv_mfma(const ushort* __restrict__ A, const ushort* __restrict__ Bt,
                   const float* __restrict__ bq, const float* __restrict__ bk,
                   const float* __restrict__ bv, ushort* __restrict__ QKV)
{
    __shared__ ushort SH[128 * 136];      // 34.8KB; loop uses first 32KB as As|Bs
    ushort* As = SH;
    ushort* Bs = SH + 128 * 64;

    const int t    = threadIdx.x;
    const int lane = t & 63;
    const int w    = t >> 6;
    const int wr   = w >> 1;
    const int wc   = w & 1;
    const int l16  = lane & 15;
    const int g    = lane >> 4;
    const int m0   = blockIdx.y * 128;
    const int n0   = blockIdx.x * 128;

    f32x4 acc[4][4];
#pragma unroll
    for (int i = 0; i < 4; ++i)
#pragma unroll
        for (int j = 0; j < 4; ++j) acc[i][j] = f32x4{0.f, 0.f, 0.f, 0.f};

    for (int kt = 0; kt < D_MODEL; kt += 64) {
        __syncthreads();
        const ushort* Ag = A  + (size_t)m0 * D_MODEL + kt;
        const ushort* Bg = Bt + (size_t)n0 * D_MODEL + kt;
#pragma unroll
        for (int it = 0; it < 4; ++it) {
            const int b   = (it * 256 + t) * 16;
            const int row = b >> 7;
            const int src = (b & 127) ^ ((row & 7) << 4);
            const int lof = (it * 256 + (t & ~63)) * 8;
            gload_lds16(Ag + (size_t)row * D_MODEL + (src >> 1), As + lof);
            gload_lds16(Bg + (size_t)row * D_MODEL + (src >> 1), Bs + lof);
        }
        __syncthreads();

#pragma unroll
        for (int kh = 0; kh < 2; ++kh) {
            short8 a[4], bfr[4];
#pragma unroll
            for (int fm = 0; fm < 4; ++fm) {
                const int row  = wr * 64 + fm * 16 + l16;
                const int byte = row * 128 + (((kh << 6) | (g << 4)) ^ ((row & 7) << 4));
                a[fm] = *(const short8*)((const char*)As + byte);
            }
#pragma unroll
            for (int fn = 0; fn < 4; ++fn) {
                const int row  = wc * 64 + fn * 16 + l16;
                const int byte = row * 128 + (((kh << 6) | (g << 4)) ^ ((row & 7) << 4));
                bfr[fn] = *(const short8*)((const char*)Bs + byte);
            }
#pragma unroll
            for (int fm = 0; fm < 4; ++fm)
#pragma unroll
                for (int fn = 0; fn < 4; ++fn)
                    acc[fm][fn] = __builtin_amdgcn_mfma_f32_16x16x32_bf16(a[fm], bfr[fn], acc[fm][fn], 0, 0, 0);
        }
    }

    const int proj = n0 >> 10;   // block-uniform

    if (proj == 2) {
        // ---- V epilogue via LDS: acc -> [nn 128][m 128] bf16, swizzled
        __syncthreads();
#pragma unroll
        for (int fm = 0; fm < 4; ++fm) {
            const int ml = wr * 64 + fm * 16 + g * 4;
#pragma unroll
            for (int fn = 0; fn < 4; ++fn) {
                const int nnl = wc * 64 + fn * 16 + l16;
                const float bn = bv[(n0 & 1023) + nnl];
                ushort4 pk;
                pk.x = f2bf(acc[fm][fn][0] + bn);
                pk.y = f2bf(acc[fm][fn][1] + bn);
                pk.z = f2bf(acc[fm][fn][2] + bn);
                pk.w = f2bf(acc[fm][fn][3] + bn);
                *(ushort4*)((char*)SH + nnl * 256 + ((ml * 2) ^ ((nnl & 15) << 4))) = pk;
            }
        }
        __syncthreads();
        const int bb  = m0 >> 11;
        const int sA0 = m0 & (SEQ - 1);
        const int ch  = t & 15;
#pragma unroll
        for (int pass = 0; pass < 8; ++pass) {
            const int rr = pass * 16 + (t >> 4);
            const int nn = (n0 & 1023) + rr;
            const int h  = nn >> 6;
            const int dh = nn & 63;
            const short8 v = *(const short8*)((const char*)SH + rr * 256 +
                                              ((ch * 16) ^ ((rr & 15) << 4)));
            *(short8*)&QKV[2 * NELT + (((size_t)(bb * N_HEADS + h)) * D_HEAD + dh) * SEQ
                           + sA0 + ch * 8] = v;
        }
        return;
    }

    // ---- Q/K epilogue via LDS: [m 128][n 128] tile, row stride 136 ushorts
    __syncthreads();
    const float sc = (proj == 0) ? QSCALE : 1.0f;
#pragma unroll
    for (int fm = 0; fm < 4; ++fm) {
        const int mlb = wr * 64 + fm * 16 + g * 4;
#pragma unroll
        for (int fn = 0; fn < 4; ++fn) {
            const int nnl = wc * 64 + fn * 16 + l16;
            const float bn = (proj == 0) ? bq[(n0 & 1023) + nnl] : bk[(n0 & 1023) + nnl];
#pragma unroll
            for (int r = 0; r < 4; ++r)
                SH[(mlb + r) * 136 + nnl] = f2bf((acc[fm][fn][r] + bn) * sc);
        }
    }
    __syncthreads();
    {
        ushort* outp = QKV + (size_t)proj * NELT;
        const int bb  = m0 >> 11;
        const int sA0 = m0 & (SEQ - 1);
        const int ch  = t & 15;
#pragma unroll
        for (int pass = 0; pass < 8; ++pass) {
            const int rr = pass * 16 + (t >> 4);
            const int nn = (n0 & 1023) + ch * 8;
            const int h  = nn >> 6;
            const int dh = nn & 63;
            const short8 v = *(const short8*)&SH[rr * 136 + ch * 8];
            *(short8*)&outp[(((size_t)(bb * N_HEADS + h)) * SEQ + sA0 + rr) * D_HEAD + dh] = v;
        }
    }
}

// ---------------------------------------------------------------------------
// Output-projection GEMM, 64(M)x128(N) tile -> 512 blocks (2/CU). (unchanged)
// ---------------------------------------------------------------------------
__global__ __launch_bounds__(256)
void gemm_out_mfma(const ushort* __restrict__ A, const ushort* __restrict__ Bt,
                   const float* __restrict__ bias, float* __restrict__ outp)
{
    __shared__ ushort As[64 * 64];
    __shared__ ushort Bs[128 * 64];

    const int t    = threadIdx.x;
    const int lane = t & 63;
    const int w    = t >> 6;
    const int l16  = lane & 15;
    const int g    = lane >> 4;
    const int m0   = blockIdx.y * 64;
    const int n0   = blockIdx.x * 128;

    f32x4 acc[4][2];
#pragma unroll
    for (int i = 0; i < 4; ++i)
#pragma unroll
        for (int j = 0; j < 2; ++j) acc[i][j] = f32x4{0.f, 0.f, 0.f, 0.f};

    for (int kt = 0; kt < D_MODEL; kt += 64) {
        __syncthreads();
        const ushort* Ag = A  + (size_t)m0 * D_MODEL + kt;
        const ushort* Bg = Bt + (size_t)n0 * D_MODEL + kt;
#pragma unroll
        for (int it = 0; it < 2; ++it) {
            const int b   = (it * 256 + t) * 16;
            const int row = b >> 7;
            const int src = (b & 127) ^ ((row & 7) << 4);
            const int lof = (it * 256 + (t & ~63)) * 8;
            gload_lds16(Ag + (size_t)row * D_MODEL + (src >> 1), As + lof);
        }
#pragma unroll
        for (int it = 0; it < 4; ++it) {
            const int b   = (it * 256 + t) * 16;
            const int row = b >> 7;
            const int src = (b & 127) ^ ((row & 7) << 4);
            const int lof = (it * 256 + (t & ~63)) * 8;
            gload_lds16(Bg + (size_t)row * D_MODEL + (src >> 1), Bs + lof);
        }
        __syncthreads();

#pragma unroll
        for (int kh = 0; kh < 2; ++kh) {
            short8 a[4], bfr[2];
#pragma unroll
            for (int fm = 0; fm < 4; ++fm) {
                const int row  = fm * 16 + l16;
                const int byte = row * 128 + (((kh << 6) | (g << 4)) ^ ((row & 7) << 4));
                a[fm] = *(const short8*)((const char*)As + byte);
            }
#pragma unroll
            for (int fn = 0; fn < 2; ++fn) {
                const int row  = w * 32 + fn * 16 + l16;
                const int byte = row * 128 + (((kh << 6) | (g << 4)) ^ ((row & 7) << 4));
                bfr[fn] = *(const short8*)((const char*)Bs + byte);
            }
#pragma unroll
            for (int fm = 0; fm < 4; ++fm)
#pragma unroll
                for (int fn = 0; fn < 2; ++fn)
                    acc[fm][fn] = __builtin_amdgcn_mfma_f32_16x16x32_bf16(a[fm], bfr[fn], acc[fm][fn], 0, 0, 0);
        }
    }

#pragma unroll
    for (int fm = 0; fm < 4; ++fm) {
        const int mb = m0 + fm * 16 + g * 4;
#pragma unroll
        for (int fn = 0; fn < 2; ++fn) {
            const int n  = n0 + w * 32 + fn * 16 + l16;
            const float bn = bias[fn * 16 + l16 + n0 + w * 32];
#pragma unroll
            for (int r = 0; r < 4; ++r)
                outp[(size_t)(mb + r) * D_MODEL + n] = acc[fm][fn][r] + bn;
        }
    }
}

// ---------------------------------------------------------------------------
// Flash attention v15: 1024 blocks x 4 waves, 64 q-rows/block (wave = 16),
// KVBLK=64 dbuf, LDS exactly 40KB -> 4 blocks/CU (4 waves/SIMD, 2x latency
// hiding vs the 512-block config). XCD-bijective: bh=(i&7)*4+(i>>3)/32 so
// each bh's K/V stays on one XCD's L2. defer-max THR=8, raw v_exp_f32,
// no setprio; l accumulates per-lane, reduced once at epilogue.
// ---------------------------------------------------------------------------
__global__ __launch_bounds__(256)
void flash_attn_mfma(const ushort* __restrict__ Q, const ushort* __restrict__ K,
                     const ushort* __restrict__ Vt, ushort* __restrict__ AO)
{
    __shared__ ushort Kl[2][64 * 64];      // [buf][key][d], 128B rows, swz (row&7)<<4
    __shared__ ushort Vl[2][64 * 64];      // [buf][d][key], 128B rows, swz (row&7)<<4
    __shared__ ushort Ps[4][16 * 64];      // per-wave P, 128B rows, swz (l16&7)<<4

    const int t    = threadIdx.x;
    const int w    = t >> 6;
    const int lane = t & 63;
    const int l16  = lane & 15;
    const int g    = lane >> 4;
    const int i    = blockIdx.x;           // 0..1023
    const int slot = i >> 3;               // 0..127
    const int bh   = (i & 7) * 4 + (slot >> 5);
    const int qt   = slot & 31;

    const int q0 = qt * 64 + w * 16;
    const size_t qkbase = (size_t)bh * SEQ * D_HEAD;
    const ushort* Vg0 = Vt + (size_t)bh * D_HEAD * SEQ;

    short8 qf[2];
    {
        const ushort* qp = Q + qkbase + (size_t)(q0 + l16) * D_HEAD + g * 8;
        qf[0] = *(const short8*)(qp);
        qf[1] = *(const short8*)(qp + 32);
    }

    f32x4 o[4];
    float m_r = -INFINITY, l_r = 0.f;
#pragma unroll
    for (int d = 0; d < 4; ++d) o[d] = f32x4{0.f, 0.f, 0.f, 0.f};

    auto stage = [&](int ktile, int b) {
        const ushort* Kg = K + qkbase + (size_t)(ktile * 64) * D_HEAD;
        const ushort* Vg = Vg0 + ktile * 64;
#pragma unroll
        for (int it = 0; it < 2; ++it) {
            const int bb  = (it * 256 + t) * 16;
            const int row = bb >> 7;
            const int src = (bb & 127) ^ ((row & 7) << 4);
            const int lof = (it * 256 + (t & ~63)) * 8;
            gload_lds16(Kg + (size_t)row * D_HEAD + (src >> 1), &Kl[b][lof]);
            gload_lds16(Vg + (size_t)row * SEQ + (src >> 1), &Vl[b][lof]);
        }
    };

    stage(0, 0);
    __syncthreads();

    const int NT = SEQ / 64;   // 32 staged tiles of 64 keys
    for (int kt = 0; kt < NT; ++kt) {
        const int buf = kt & 1;
        if (kt + 1 < NT) stage(kt + 1, buf ^ 1);

        // ---- K fragments from LDS
        short8 kf[4][2];
#pragma unroll
        for (int nt = 0; nt < 4; ++nt) {
            const int row = nt * 16 + l16;
#pragma unroll
            for (int ks = 0; ks < 2; ++ks) {
                const int byte = row * 128 + (((ks * 64) | (g * 16)) ^ ((row & 7) << 4));
                kf[nt][ks] = *(const short8*)((const char*)&Kl[buf][0] + byte);
            }
        }
        // ---- V fragments from LDS
        short8 vf[4][2];
#pragma unroll
        for (int dt = 0; dt < 4; ++dt) {
            const int row = dt * 16 + l16;
#pragma unroll
            for (int ks = 0; ks < 2; ++ks) {
                const int byte = row * 128 + (((ks * 64) | (g * 16)) ^ ((row & 7) << 4));
                vf[dt][ks] = *(const short8*)((const char*)&Vl[buf][0] + byte);
            }
        }

        // ---- S^T = K @ Q^T (log2 domain)
        f32x4 st[4];
#pragma unroll
        for (int nt = 0; nt < 4; ++nt) {
            f32x4 a = f32x4{0.f, 0.f, 0.f, 0.f};
            a = __builtin_amdgcn_mfma_f32_16x16x32_bf16(kf[nt][0], qf[0], a, 0, 0, 0);
            a = __builtin_amdgcn_mfma_f32_16x16x32_bf16(kf[nt][1], qf[1], a, 0, 0, 0);
            st[nt] = a;
        }

        // ---- softmax (row q = l16; defer-max THR=8)
        float pmax = st[0][0];
#pragma unroll
        for (int nt = 0; nt < 4; ++nt)
#pragma unroll
            for (int r = 0; r < 4; ++r) pmax = fmaxf(pmax, st[nt][r]);
        pmax = fmaxf(pmax, __shfl_xor(pmax, 16, 64));
        pmax = fmaxf(pmax, __shfl_xor(pmax, 32, 64));

        if (__any(pmax - m_r > 8.f)) {
            const float mnew  = fmaxf(m_r, pmax);
            const float alpha = exp2_raw(m_r - mnew);
            m_r = mnew;
            l_r *= alpha;                  // per-lane partial, alpha row-uniform
            float ar[4];
#pragma unroll
            for (int r = 0; r < 4; ++r) ar[r] = __shfl(alpha, g * 4 + r, 64);
#pragma unroll
            for (int dt = 0; dt < 4; ++dt)
#pragma unroll
                for (int r = 0; r < 4; ++r) o[dt][r] *= ar[r];
        }

        float rs = 0.f;
#pragma unroll
        for (int nt = 0; nt < 4; ++nt) {
            ushort4 pk;
#pragma unroll
            for (int r = 0; r < 4; ++r) {
                const float p = exp2_raw(st[nt][r] - m_r);
                rs += p;
                ((ushort*)&pk)[r] = f2bf(p);
            }
            const int pb = (nt * 32 + g * 8) ^ ((l16 & 7) << 4);
            *(ushort4*)((char*)&Ps[w][0] + l16 * 128 + pb) = pk;
        }
        l_r += rs;                         // per-lane; cross-lane at epilogue

        // ---- O += P @ V (swizzled P read)
#pragma unroll
        for (int ks = 0; ks < 2; ++ks) {
            const int rb = (ks * 64 + g * 16) ^ ((l16 & 7) << 4);
            const short8 pf = *(const short8*)((const char*)&Ps[w][0] + l16 * 128 + rb);
#pragma unroll
            for (int dt = 0; dt < 4; ++dt)
                o[dt] = __builtin_amdgcn_mfma_f32_16x16x32_bf16(pf, vf[dt][ks], o[dt], 0, 0, 0);
        }

        __syncthreads();   // staging drained (vmcnt0); all reads of buf done
    }

    // ---- epilogue: cross-lane l reduce once, then AO[b][s][h*64+d] bf16
    float lt = l_r;
    lt += __shfl_xor(lt, 16, 64);
    lt += __shfl_xor(lt, 32, 64);
    float lr_row[4];
#pragma unroll
    for (int r = 0; r < 4; ++r) lr_row[r] = __shfl(lt, g * 4 + r, 64);

    const int b = bh >> 4;
    const int h = bh & 15;
#pragma unroll
    for (int r = 0; r < 4; ++r) {
        const float inv = 1.f / lr_row[r];
        const size_t row = (size_t)b * SEQ + q0 + g * 4 + r;
#pragma unroll
        for (int dt = 0; dt < 4; ++dt)
            AO[row * D_MODEL + h * D_HEAD + dt * 16 + l16] = f2bf(o[dt][r] * inv);
    }
}

// ---------------------------------------------------------------------------
extern "C" void kernel_launch(void* const* d_in, const int* in_sizes, int n_in,
                              void* d_out, int out_size, void* d_ws, size_t ws_size,
                              hipStream_t stream)
{
    const float* x  = (const float*)d_in[0];
    const float* Wq = (const float*)d_in[1];
    const float* bq = (const float*)d_in[2];
    const float* Wk = (const float*)d_in[3];
    const float* bk = (const float*)d_in[4];
    const float* Wv = (const float*)d_in[5];
    const float* bv = (const float*)d_in[6];
    const float* Wo = (const float*)d_in[7];
    const float* bo = (const float*)d_in[8];
    float* out = (float*)d_out;

    const size_t WELT = (size_t)D_MODEL * D_MODEL;   // 1M
    ushort* xb  = (ushort*)d_ws;        // [0,1N): x bf16
    ushort* Wqt = xb + NELT;            // [1N,2N): Wq/Wk/Wv/Wo transposed
    ushort* Wot = Wqt + 3 * WELT;
    ushort* Qb  = xb + 2 * NELT;        // [2N,3N): Q head layout (pre-scaled)
    ushort* Kb  = Qb + NELT;            // [3N,4N)
    ushort* Vtb = Kb + NELT;            // [4N,5N): V transposed head layout
    ushort* AOb = xb + 5 * NELT;        // [5N,6N): attention out bf16

    prep_kernel<<<dim3(D_MODEL / 64, D_MODEL / 64, 5), 256, 0, stream>>>(x, Wq, Wk, Wv, Wo, xb, Wqt);
    gemm_qkv_mfma<<<dim3(3 * D_MODEL / 128, M_TOT / 128), 256, 0, stream>>>(xb, Wqt, bq, bk, bv, Qb);
    flash_attn_mfma<<<dim3(1024), 256, 0, stream>>>(Qb, Kb, Vtb, AOb);
    gemm_out_mfma<<<dim3(D_MODEL / 128, M_TOT / 64), 256, 0, stream>>>(AOb, Wot, bo, out);
}

// Round 20
// 125.141 us; speedup vs baseline: 1.0668x; 1.0668x over previous
//
#include <hip/hip_runtime.h>
#include <hip/hip_bf16.h>
#include <cmath>

#define D_MODEL 1024
#define N_HEADS 16
#define D_HEAD  64
#define BATCH   2
#define SEQ     2048
#define M_TOT   (BATCH*SEQ)   // 4096
#define NELT    ((size_t)M_TOT * D_MODEL)   // 4M elements

typedef __attribute__((ext_vector_type(8))) short short8;   // 8 bf16 (4 VGPRs)
typedef __attribute__((ext_vector_type(4))) float f32x4;

// Q pre-scale: 1/sqrt(64) * log2(e)  (softmax computed base-2)
#define QSCALE (0.125f * 1.44269504088896f)

static __device__ __forceinline__ ushort f2bf(float f) {
    __hip_bfloat16 h = __float2bfloat16(f);   // RNE
    return *reinterpret_cast<ushort*>(&h);
}

// Raw v_exp_f32 (2^x) — no libm denormal-fixup wrapper (round-13 win).
static __device__ __forceinline__ float exp2_raw(float x) {
    return __builtin_amdgcn_exp2f(x);
}

static __device__ __forceinline__ void gload_lds16(const void* g, void* l) {
    __builtin_amdgcn_global_load_lds((const __attribute__((address_space(1))) unsigned*)g,
                                     (__attribute__((address_space(3))) unsigned*)l,
                                     16, 0, 0);
}

// ---------------------------------------------------------------------------
// prep: z<4 -> transpose+convert weight z to Wt [N][K] bf16;
//       z==4 -> convert a slab of x to bf16.
// ---------------------------------------------------------------------------
__global__ __launch_bounds__(256)
void prep_kernel(const float* __restrict__ x,
                 const float* __restrict__ W0, const float* __restrict__ W1,
                 const float* __restrict__ W2, const float* __restrict__ W3,
                 ushort* __restrict__ xb, ushort* __restrict__ Wt0)
{
    __shared__ float Ts[64][65];
    const int z = blockIdx.z;
    const int t = threadIdx.x;

    if (z == 4) {
        const int slab = blockIdx.y * 16 + blockIdx.x;
#pragma unroll
        for (int u = 0; u < 16; ++u) {
            const int i = slab * 4096 + u * 256 + t;
            const float4 v = ((const float4*)x)[i];
            ushort4 uo;
            uo.x = f2bf(v.x); uo.y = f2bf(v.y); uo.z = f2bf(v.z); uo.w = f2bf(v.w);
            ((ushort4*)xb)[i] = uo;
        }
        return;
    }

    const float* W = (z == 0) ? W0 : (z == 1) ? W1 : (z == 2) ? W2 : W3;
    ushort* Wt = Wt0 + (size_t)z * D_MODEL * D_MODEL;

    const int n0 = blockIdx.x * 64;
    const int k0 = blockIdx.y * 64;
    const int rr = t >> 4;
    const int c4 = (t & 15) * 4;

#pragma unroll
    for (int i = 0; i < 4; ++i) {
        const int r = rr + i * 16;
        const float4 v = *(const float4*)&W[(size_t)(k0 + r) * D_MODEL + n0 + c4];
        Ts[r][c4 + 0] = v.x; Ts[r][c4 + 1] = v.y;
        Ts[r][c4 + 2] = v.z; Ts[r][c4 + 3] = v.w;
    }
    __syncthreads();
#pragma unroll
    for (int i = 0; i < 4; ++i) {
        const int nn = rr + i * 16;
        ushort4 u;
        u.x = f2bf(Ts[c4 + 0][nn]); u.y = f2bf(Ts[c4 + 1][nn]);
        u.z = f2bf(Ts[c4 + 2][nn]); u.w = f2bf(Ts[c4 + 3][nn]);
        *(ushort4*)&Wt[(size_t)(n0 + nn) * D_MODEL + k0 + c4] = u;
    }
}

// ---------------------------------------------------------------------------
// Merged QKV GEMM: bf16 MFMA, 128x128 tile, BK=64, 4 waves.
// Q/K epilogue routed through LDS ([m][n] tile, stride 136) -> 16B stores.
// V epilogue via [n][m] LDS tile -> 256B-contiguous stores.
// ---------------------------------------------------------------------------
__global__ __launch_bounds__(256)
void gemm_qkv_mfma(const ushort* __restrict__ A, const ushort* __restrict__ Bt,
                   const float* __restrict__ bq, const float* __restrict__ bk,
                   const float* __restrict__ bv, ushort* __restrict__ QKV)
{
    __shared__ ushort SH[128 * 136];      // 34.8KB; loop uses first 32KB as As|Bs
    ushort* As = SH;
    ushort* Bs = SH + 128 * 64;

    const int t    = threadIdx.x;
    const int lane = t & 63;
    const int w    = t >> 6;
    const int wr   = w >> 1;
    const int wc   = w & 1;
    const int l16  = lane & 15;
    const int g    = lane >> 4;
    const int m0   = blockIdx.y * 128;
    const int n0   = blockIdx.x * 128;

    f32x4 acc[4][4];
#pragma unroll
    for (int i = 0; i < 4; ++i)
#pragma unroll
        for (int j = 0; j < 4; ++j) acc[i][j] = f32x4{0.f, 0.f, 0.f, 0.f};

    for (int kt = 0; kt < D_MODEL; kt += 64) {
        __syncthreads();
        const ushort* Ag = A  + (size_t)m0 * D_MODEL + kt;
        const ushort* Bg = Bt + (size_t)n0 * D_MODEL + kt;
#pragma unroll
        for (int it = 0; it < 4; ++it) {
            const int b   = (it * 256 + t) * 16;
            const int row = b >> 7;
            const int src = (b & 127) ^ ((row & 7) << 4);
            const int lof = (it * 256 + (t & ~63)) * 8;
            gload_lds16(Ag + (size_t)row * D_MODEL + (src >> 1), As + lof);
            gload_lds16(Bg + (size_t)row * D_MODEL + (src >> 1), Bs + lof);
        }
        __syncthreads();

#pragma unroll
        for (int kh = 0; kh < 2; ++kh) {
            short8 a[4], bfr[4];
#pragma unroll
            for (int fm = 0; fm < 4; ++fm) {
                const int row  = wr * 64 + fm * 16 + l16;
                const int byte = row * 128 + (((kh << 6) | (g << 4)) ^ ((row & 7) << 4));
                a[fm] = *(const short8*)((const char*)As + byte);
            }
#pragma unroll
            for (int fn = 0; fn < 4; ++fn) {
                const int row  = wc * 64 + fn * 16 + l16;
                const int byte = row * 128 + (((kh << 6) | (g << 4)) ^ ((row & 7) << 4));
                bfr[fn] = *(const short8*)((const char*)Bs + byte);
            }
#pragma unroll
            for (int fm = 0; fm < 4; ++fm)
#pragma unroll
                for (int fn = 0; fn < 4; ++fn)
                    acc[fm][fn] = __builtin_amdgcn_mfma_f32_16x16x32_bf16(a[fm], bfr[fn], acc[fm][fn], 0, 0, 0);
        }
    }

    const int proj = n0 >> 10;   // block-uniform

    if (proj == 2) {
        // ---- V epilogue via LDS: acc -> [nn 128][m 128] bf16, swizzled
        __syncthreads();
#pragma unroll
        for (int fm = 0; fm < 4; ++fm) {
            const int ml = wr * 64 + fm * 16 + g * 4;
#pragma unroll
            for (int fn = 0; fn < 4; ++fn) {
                const int nnl = wc * 64 + fn * 16 + l16;
                const float bn = bv[(n0 & 1023) + nnl];
                ushort4 pk;
                pk.x = f2bf(acc[fm][fn][0] + bn);
                pk.y = f2bf(acc[fm][fn][1] + bn);
                pk.z = f2bf(acc[fm][fn][2] + bn);
                pk.w = f2bf(acc[fm][fn][3] + bn);
                *(ushort4*)((char*)SH + nnl * 256 + ((ml * 2) ^ ((nnl & 15) << 4))) = pk;
            }
        }
        __syncthreads();
        const int bb  = m0 >> 11;
        const int sA0 = m0 & (SEQ - 1);
        const int ch  = t & 15;
#pragma unroll
        for (int pass = 0; pass < 8; ++pass) {
            const int rr = pass * 16 + (t >> 4);
            const int nn = (n0 & 1023) + rr;
            const int h  = nn >> 6;
            const int dh = nn & 63;
            const short8 v = *(const short8*)((const char*)SH + rr * 256 +
                                              ((ch * 16) ^ ((rr & 15) << 4)));
            *(short8*)&QKV[2 * NELT + (((size_t)(bb * N_HEADS + h)) * D_HEAD + dh) * SEQ
                           + sA0 + ch * 8] = v;
        }
        return;
    }

    // ---- Q/K epilogue via LDS: [m 128][n 128] tile, row stride 136 ushorts
    __syncthreads();
    const float sc = (proj == 0) ? QSCALE : 1.0f;
#pragma unroll
    for (int fm = 0; fm < 4; ++fm) {
        const int mlb = wr * 64 + fm * 16 + g * 4;
#pragma unroll
        for (int fn = 0; fn < 4; ++fn) {
            const int nnl = wc * 64 + fn * 16 + l16;
            const float bn = (proj == 0) ? bq[(n0 & 1023) + nnl] : bk[(n0 & 1023) + nnl];
#pragma unroll
            for (int r = 0; r < 4; ++r)
                SH[(mlb + r) * 136 + nnl] = f2bf((acc[fm][fn][r] + bn) * sc);
        }
    }
    __syncthreads();
    {
        ushort* outp = QKV + (size_t)proj * NELT;
        const int bb  = m0 >> 11;
        const int sA0 = m0 & (SEQ - 1);
        const int ch  = t & 15;
#pragma unroll
        for (int pass = 0; pass < 8; ++pass) {
            const int rr = pass * 16 + (t >> 4);
            const int nn = (n0 & 1023) + ch * 8;
            const int h  = nn >> 6;
            const int dh = nn & 63;
            const short8 v = *(const short8*)&SH[rr * 136 + ch * 8];
            *(short8*)&outp[(((size_t)(bb * N_HEADS + h)) * SEQ + sA0 + rr) * D_HEAD + dh] = v;
        }
    }
}

// ---------------------------------------------------------------------------
// Output-projection GEMM, 64(M)x128(N) tile -> 512 blocks (2/CU).
// ---------------------------------------------------------------------------
__global__ __launch_bounds__(256)
void gemm_out_mfma(const ushort* __restrict__ A, const ushort* __restrict__ Bt,
                   const float* __restrict__ bias, float* __restrict__ outp)
{
    __shared__ ushort As[64 * 64];
    __shared__ ushort Bs[128 * 64];

    const int t    = threadIdx.x;
    const int lane = t & 63;
    const int w    = t >> 6;
    const int l16  = lane & 15;
    const int g    = lane >> 4;
    const int m0   = blockIdx.y * 64;
    const int n0   = blockIdx.x * 128;

    f32x4 acc[4][2];
#pragma unroll
    for (int i = 0; i < 4; ++i)
#pragma unroll
        for (int j = 0; j < 2; ++j) acc[i][j] = f32x4{0.f, 0.f, 0.f, 0.f};

    for (int kt = 0; kt < D_MODEL; kt += 64) {
        __syncthreads();
        const ushort* Ag = A  + (size_t)m0 * D_MODEL + kt;
        const ushort* Bg = Bt + (size_t)n0 * D_MODEL + kt;
#pragma unroll
        for (int it = 0; it < 2; ++it) {
            const int b   = (it * 256 + t) * 16;
            const int row = b >> 7;
            const int src = (b & 127) ^ ((row & 7) << 4);
            const int lof = (it * 256 + (t & ~63)) * 8;
            gload_lds16(Ag + (size_t)row * D_MODEL + (src >> 1), As + lof);
        }
#pragma unroll
        for (int it = 0; it < 4; ++it) {
            const int b   = (it * 256 + t) * 16;
            const int row = b >> 7;
            const int src = (b & 127) ^ ((row & 7) << 4);
            const int lof = (it * 256 + (t & ~63)) * 8;
            gload_lds16(Bg + (size_t)row * D_MODEL + (src >> 1), Bs + lof);
        }
        __syncthreads();

#pragma unroll
        for (int kh = 0; kh < 2; ++kh) {
            short8 a[4], bfr[2];
#pragma unroll
            for (int fm = 0; fm < 4; ++fm) {
                const int row  = fm * 16 + l16;
                const int byte = row * 128 + (((kh << 6) | (g << 4)) ^ ((row & 7) << 4));
                a[fm] = *(const short8*)((const char*)As + byte);
            }
#pragma unroll
            for (int fn = 0; fn < 2; ++fn) {
                const int row  = w * 32 + fn * 16 + l16;
                const int byte = row * 128 + (((kh << 6) | (g << 4)) ^ ((row & 7) << 4));
                bfr[fn] = *(const short8*)((const char*)Bs + byte);
            }
#pragma unroll
            for (int fm = 0; fm < 4; ++fm)
#pragma unroll
                for (int fn = 0; fn < 2; ++fn)
                    acc[fm][fn] = __builtin_amdgcn_mfma_f32_16x16x32_bf16(a[fm], bfr[fn], acc[fm][fn], 0, 0, 0);
        }
    }

#pragma unroll
    for (int fm = 0; fm < 4; ++fm) {
        const int mb = m0 + fm * 16 + g * 4;
#pragma unroll
        for (int fn = 0; fn < 2; ++fn) {
            const int n  = n0 + w * 32 + fn * 16 + l16;
            const float bn = bias[n];
#pragma unroll
            for (int r = 0; r < 4; ++r)
                outp[(size_t)(mb + r) * D_MODEL + n] = acc[fm][fn][r] + bn;
        }
    }
}

// ---------------------------------------------------------------------------
// Flash attention (round-17 measured best, 64.5us): 512 blocks, 4 waves,
// wave = 32 q-rows (2x16 sub-tiles), KVBLK=128 dbuf LDS staging, defer-max
// THR=8, raw v_exp_f32, no setprio. XCD swizzle: bh=(i&7)*4+(i>>3)/16 keeps
// each (b,h)'s K/V on one XCD's L2 (FETCH 70MB -> 12.4MB, measured).
// ---------------------------------------------------------------------------
__global__ __launch_bounds__(256)
void flash_attn_mfma(const ushort* __restrict__ Q, const ushort* __restrict__ K,
                     const ushort* __restrict__ Vt, ushort* __restrict__ AO)
{
    __shared__ ushort Kl[2][128 * 64];     // [buf][key][d], 128B rows, swz (row&7)<<4
    __shared__ ushort Vl[2][64 * 128];     // [buf][d][key], 256B rows, swz (row&15)<<4
    __shared__ ushort Ps[4][16 * 64];      // per-wave P, 128B rows, swz (l16&7)<<4

    const int t    = threadIdx.x;
    const int w    = t >> 6;
    const int lane = t & 63;
    const int l16  = lane & 15;
    const int g    = lane >> 4;
    const int i    = blockIdx.x;           // 0..511
    const int slot = i >> 3;
    const int bh   = (i & 7) * 4 + (slot >> 4);
    const int qt   = slot & 15;

    const size_t qkbase = (size_t)bh * SEQ * D_HEAD;
    const ushort* Vg0 = Vt + (size_t)bh * D_HEAD * SEQ;

    short8 qf[2][2];
#pragma unroll
    for (int tt = 0; tt < 2; ++tt) {
        const int q0 = qt * 128 + w * 32 + tt * 16;
        const ushort* qp = Q + qkbase + (size_t)(q0 + l16) * D_HEAD + g * 8;
        qf[tt][0] = *(const short8*)(qp);
        qf[tt][1] = *(const short8*)(qp + 32);
    }

    f32x4 o[2][4];
    float m_r[2], l_r[2];
#pragma unroll
    for (int tt = 0; tt < 2; ++tt) {
        m_r[tt] = -INFINITY; l_r[tt] = 0.f;
#pragma unroll
        for (int d = 0; d < 4; ++d) o[tt][d] = f32x4{0.f, 0.f, 0.f, 0.f};
    }

    auto stage = [&](int ktile, int b) {
        const ushort* Kg = K + qkbase + (size_t)(ktile * 128) * D_HEAD;
        const ushort* Vg = Vg0 + ktile * 128;
#pragma unroll
        for (int it = 0; it < 4; ++it) {
            const int bb   = (it * 256 + t) * 16;
            const int lof  = (it * 256 + (t & ~63)) * 8;
            const int rowK = bb >> 7;
            const int srcK = (bb & 127) ^ ((rowK & 7) << 4);
            gload_lds16(Kg + (size_t)rowK * D_HEAD + (srcK >> 1), &Kl[b][lof]);
            const int rowV = bb >> 8;
            const int srcV = (bb & 255) ^ ((rowV & 15) << 4);
            gload_lds16(Vg + (size_t)rowV * SEQ + (srcV >> 1), &Vl[b][lof]);
        }
    };

    stage(0, 0);
    __syncthreads();

    const int NT = SEQ / 128;   // 16 staged tiles of 128 keys
    for (int kt = 0; kt < NT; ++kt) {
        const int buf = kt & 1;
        if (kt + 1 < NT) stage(kt + 1, buf ^ 1);

#pragma unroll
        for (int h2 = 0; h2 < 2; ++h2) {
            short8 kf[4][2];
#pragma unroll
            for (int nt = 0; nt < 4; ++nt) {
                const int row = h2 * 64 + nt * 16 + l16;
#pragma unroll
                for (int ks = 0; ks < 2; ++ks) {
                    const int byte = row * 128 + (((ks * 64) | (g * 16)) ^ ((row & 7) << 4));
                    kf[nt][ks] = *(const short8*)((const char*)&Kl[buf][0] + byte);
                }
            }

            short8 vf[4][2];
#pragma unroll
            for (int dt = 0; dt < 4; ++dt) {
                const int row = dt * 16 + l16;
#pragma unroll
                for (int ks = 0; ks < 2; ++ks) {
                    const int byte = row * 256 + ((h2 * 128 + ks * 64 + g * 16) ^ ((row & 15) << 4));
                    vf[dt][ks] = *(const short8*)((const char*)&Vl[buf][0] + byte);
                }
            }

            f32x4 st[2][4];
#pragma unroll
            for (int tt = 0; tt < 2; ++tt)
#pragma unroll
                for (int nt = 0; nt < 4; ++nt) {
                    f32x4 a = f32x4{0.f, 0.f, 0.f, 0.f};
                    a = __builtin_amdgcn_mfma_f32_16x16x32_bf16(kf[nt][0], qf[tt][0], a, 0, 0, 0);
                    a = __builtin_amdgcn_mfma_f32_16x16x32_bf16(kf[nt][1], qf[tt][1], a, 0, 0, 0);
                    st[tt][nt] = a;
                }

#pragma unroll
            for (int tt = 0; tt < 2; ++tt) {
                float pmax = st[tt][0][0];
#pragma unroll
                for (int nt = 0; nt < 4; ++nt)
#pragma unroll
                    for (int r = 0; r < 4; ++r) pmax = fmaxf(pmax, st[tt][nt][r]);
                pmax = fmaxf(pmax, __shfl_xor(pmax, 16, 64));
                pmax = fmaxf(pmax, __shfl_xor(pmax, 32, 64));

                if (__any(pmax - m_r[tt] > 8.f)) {
                    const float mnew  = fmaxf(m_r[tt], pmax);
                    const float alpha = exp2_raw(m_r[tt] - mnew);
                    m_r[tt] = mnew;
                    l_r[tt] *= alpha;
                    float ar[4];
#pragma unroll
                    for (int r = 0; r < 4; ++r) ar[r] = __shfl(alpha, g * 4 + r, 64);
#pragma unroll
                    for (int dt = 0; dt < 4; ++dt)
#pragma unroll
                        for (int r = 0; r < 4; ++r) o[tt][dt][r] *= ar[r];
                }

                float rs = 0.f;
#pragma unroll
                for (int nt = 0; nt < 4; ++nt) {
                    ushort4 pk;
#pragma unroll
                    for (int r = 0; r < 4; ++r) {
                        const float p = exp2_raw(st[tt][nt][r] - m_r[tt]);
                        rs += p;
                        ((ushort*)&pk)[r] = f2bf(p);
                    }
                    const int pb = (nt * 32 + g * 8) ^ ((l16 & 7) << 4);
                    *(ushort4*)((char*)&Ps[w][0] + l16 * 128 + pb) = pk;
                }
                rs += __shfl_xor(rs, 16, 64);
                rs += __shfl_xor(rs, 32, 64);
                l_r[tt] += rs;

#pragma unroll
                for (int ks = 0; ks < 2; ++ks) {
                    const int rb = (ks * 64 + g * 16) ^ ((l16 & 7) << 4);
                    const short8 pf = *(const short8*)((const char*)&Ps[w][0] + l16 * 128 + rb);
#pragma unroll
                    for (int dt = 0; dt < 4; ++dt)
                        o[tt][dt] = __builtin_amdgcn_mfma_f32_16x16x32_bf16(pf, vf[dt][ks], o[tt][dt], 0, 0, 0);
                }
            }
        }

        __syncthreads();   // staging drained (vmcnt0); all reads of buf done
    }

    // ---- epilogue: AO[b][s][h*64+d] bf16
    const int b = bh >> 4;
    const int h = bh & 15;
#pragma unroll
    for (int tt = 0; tt < 2; ++tt) {
        const int q0 = qt * 128 + w * 32 + tt * 16;
        float lr_row[4];
#pragma unroll
        for (int r = 0; r < 4; ++r) lr_row[r] = __shfl(l_r[tt], g * 4 + r, 64);
#pragma unroll
        for (int r = 0; r < 4; ++r) {
            const float inv = 1.f / lr_row[r];
            const size_t row = (size_t)b * SEQ + q0 + g * 4 + r;
#pragma unroll
            for (int dt = 0; dt < 4; ++dt)
                AO[row * D_MODEL + h * D_HEAD + dt * 16 + l16] = f2bf(o[tt][dt][r] * inv);
        }
    }
}

// ---------------------------------------------------------------------------
extern "C" void kernel_launch(void* const* d_in, const int* in_sizes, int n_in,
                              void* d_out, int out_size, void* d_ws, size_t ws_size,
                              hipStream_t stream)
{
    const float* x  = (const float*)d_in[0];
    const float* Wq = (const float*)d_in[1];
    const float* bq = (const float*)d_in[2];
    const float* Wk = (const float*)d_in[3];
    const float* bk = (const float*)d_in[4];
    const float* Wv = (const float*)d_in[5];
    const float* bv = (const float*)d_in[6];
    const float* Wo = (const float*)d_in[7];
    const float* bo = (const float*)d_in[8];
    float* out = (float*)d_out;

    const size_t WELT = (size_t)D_MODEL * D_MODEL;   // 1M
    ushort* xb  = (ushort*)d_ws;        // [0,1N): x bf16
    ushort* Wqt = xb + NELT;            // [1N,2N): Wq/Wk/Wv/Wo transposed
    ushort* Wot = Wqt + 3 * WELT;
    ushort* Qb  = xb + 2 * NELT;        // [2N,3N): Q head layout (pre-scaled)
    ushort* Kb  = Qb + NELT;            // [3N,4N)
    ushort* Vtb = Kb + NELT;            // [4N,5N): V transposed head layout
    ushort* AOb = xb + 5 * NELT;        // [5N,6N): attention out bf16

    prep_kernel<<<dim3(D_MODEL / 64, D_MODEL / 64, 5), 256, 0, stream>>>(x, Wq, Wk, Wv, Wo, xb, Wqt);
    gemm_qkv_mfma<<<dim3(3 * D_MODEL / 128, M_TOT / 128), 256, 0, stream>>>(xb, Wqt, bq, bk, bv, Qb);
    flash_attn_mfma<<<dim3(512), 256, 0, stream>>>(Qb, Kb, Vtb, AOb);
    gemm_out_mfma<<<dim3(D_MODEL / 128, M_TOT / 64), 256, 0, stream>>>(AOb, Wot, bo, out);
}